// Round 9
// baseline (327.634 us; speedup 1.0000x reference)
//
#include <hip/hip_runtime.h>

typedef unsigned short u16;
typedef unsigned int u32;
typedef float f32x4 __attribute__((ext_vector_type(4)));
typedef short bf16x8 __attribute__((ext_vector_type(8)));

#define NB 8
#define FH 37
#define FW 50
#define FHW 1850
#define MTOT 14800
#define CIN 512
#define KTOT 4608
#define HP 39
#define WP 52
#define ANCH 16650
#define NG 20

// k_pre block ranges
#define ZB 356            // pad-ring zero
#define WTB 512           // w3 repack (LDS transpose, 1 block per n)
#define WHB 128           // head-weight repack
#define TRB 3712          // NHWC transpose: 58 hw x 8 ctile x 8 img
#define IOB 528           // 66 x 8 iou blocks (tail of k_pre)
#define PRE_TOT (ZB + WTB + WHB + TRB + IOB)

#define CONVB 960         // 116 mb x 8 nb (XCD swizzle; 32 dead blocks)

// ---------- helpers ----------
__device__ __forceinline__ u16 f2bf(float f) {
    u32 u = __float_as_uint(f);
    u += 0x7fffu + ((u >> 16) & 1u);   // round-to-nearest-even
    return (u16)(u >> 16);
}

__device__ __forceinline__ void gl2lds16(const u16* g, u16* l) {
    __builtin_amdgcn_global_load_lds((const __attribute__((address_space(1))) void*)(g),
                                     (__attribute__((address_space(3))) void*)(l),
                                     16, 0, 0);
}

__device__ __forceinline__ void anchor_box(int a, float& x1, float& y1, float& x2, float& y2) {
    int x = a / 333;
    int rem = a - x * 333;
    int y = rem / 9;
    int r2 = rem - y * 9;
    int si = r2 / 3;
    int bi = r2 - si * 3;
    float s = (float)(8 << si);
    float fx = (float)x, fy = (float)y;
    float ax1, ay1, ax2, ay2;
    if (bi == 0)      { float h = s * 0.5f;  ax1 = fx - h; ay1 = fy - h; ax2 = fx + h; ay2 = fy + h; }
    else if (bi == 1) { float q = s * 0.25f; ax1 = fx - s; ay1 = fy - q; ax2 = fx + s; ay2 = fy + q; }
    else              { float q = s * 0.25f; ax1 = fx - q; ay1 = fy - s; ax2 = fx + q; ay2 = fy + s; }
    x1 = ax1 * 16.f; y1 = ay1 * 16.f; x2 = ax2 * 16.f; y2 = ay2 * 16.f;
}

// ---------- fused prep + IoU ----------
__global__ __launch_bounds__(256) void k_pre(u16* __restrict__ apad,
                                             const float* __restrict__ w3, u16* __restrict__ wt,
                                             const float* __restrict__ wc, const float* __restrict__ wb,
                                             u16* __restrict__ whd,
                                             const float* __restrict__ feats,
                                             const float* __restrict__ gt, const float* __restrict__ im,
                                             float* __restrict__ iou_out, float* __restrict__ lab) {
    __shared__ __attribute__((aligned(16))) char smraw[20864];
    __shared__ int idxs;
    int blk = blockIdx.x;
    int t = threadIdx.x;

    if (blk < ZB) {
        // zero only the 1-px pad ring (interior overwritten by transpose)
        uint4* apad4 = (uint4*)apad;
        int i = blk * 256 + t;               // < 91136
        int img = i / 11392;
        int r = i - img * 11392;
        int u4;
        if (r < 3328) u4 = r;                                   // row 0
        else if (r < 6656) u4 = 126464 + (r - 3328);            // row 38
        else {
            int rp = r - 6656;
            int h = 1 + (rp >> 7);
            int c2 = rp & 127;
            int col = (c2 & 64) ? 51 : 0;
            u4 = (h * 52 + col) * 64 + (c2 & 63);
        }
        apad4[img * 129792 + u4] = make_uint4(0u, 0u, 0u, 0u);
    } else if (blk < ZB + WTB) {
        // w3[n] (512,3,3) -> wt[n][tap*512+ci], coalesced via LDS transpose
        float* lt = (float*)smraw;           // 4608 floats
        int n = blk - ZB;
        const float* src = w3 + n * KTOT;
        for (int i = t; i < KTOT; i += 256) lt[i] = src[i];
        __syncthreads();
        u16* dst = wt + n * KTOT;
        for (int o = t; o < KTOT; o += 256) {
            int tap = o >> 9, ci = o & 511;
            dst[o] = f2bf(lt[ci * 9 + tap]);
        }
    } else if (blk < ZB + WTB + WHB) {
        int i = (blk - ZB - WTB) * 256 + t;
        int n = i >> 9;
        int ci = i & 511;
        float v = 0.f;
        if (n < 18) v = wc[n * 512 + ci];
        else if (n < 54) v = wb[(n - 18) * 512 + ci];
        whd[i] = f2bf(v);
    } else if (blk < ZB + WTB + WHB + TRB) {
        // feats (B,512,37,50) f32 -> apad (B,39,52,512) bf16 interior.
        // Tile: 32 hw x 64 c; stores pack 2 channels/lane (u32, 128-B segments).
        float* tile = (float*)smraw;         // 64 x 33 floats
        int q = blk - ZB - WTB - WHB;
        int xt = q % 58;
        int r2 = q / 58;
        int ct = r2 & 7;                     // 8 c-tiles of 64
        int img = r2 >> 3;
        int hw0 = xt * 32, c0 = ct * 64;
        int lx = t & 31, ly = t >> 5;        // ly 0..7
        #pragma unroll
        for (int rr = 0; rr < 8; rr++) {
            int cl = ly + rr * 8;            // 0..63
            int hw = hw0 + lx;
            if (hw < FHW) tile[cl * 33 + lx] = feats[(img * 512 + c0 + cl) * FHW + hw];
        }
        __syncthreads();
        #pragma unroll
        for (int rr = 0; rr < 4; rr++) {
            int hwl = ly + rr * 8;           // 0..31
            int hw2 = hw0 + hwl;
            if (hw2 < FHW) {
                int h = hw2 / FW, w = hw2 - h * FW;
                float v0 = tile[(2 * lx) * 33 + hwl];
                float v1 = tile[(2 * lx + 1) * 33 + hwl];
                u32 pk = (u32)f2bf(v0) | ((u32)f2bf(v1) << 16);
                u32* dst = (u32*)&apad[(((img * HP) + h + 1) * WP + (w + 1)) * 512 + c0];
                dst[lx] = pk;
            }
        }
    } else {
        // IoU matrix + labels (idx fused)
        float* g4 = (float*)smraw;           // 80 floats
        float* imv = g4 + 80;                // 2
        float* buf = g4 + 84;                // 256*20 floats (total 20816 B)
        int q = blk - ZB - WTB - WHB - TRB;
        int at = q % 66;
        int b = q / 66;
        if (t < NG * 4) g4[t] = gt[b * NG * 4 + t];
        if (t < 2) imv[t] = im[t];
        __syncthreads();
        if (t == 0) {
            float x1, y1, x2, y2;
            anchor_box(19, x1, y1, x2, y2);
            bool inside = (x1 >= 0.f) && (y1 >= 0.f) && (x2 < imv[1]) && (y2 < imv[0]);
            float aa = (x2 - x1) * (y2 - y1);
            float best = -1.f; int bg = 0;
            for (int g2 = 0; g2 < NG; g2++) {
                float gx1 = g4[g2 * 4], gy1 = g4[g2 * 4 + 1], gx2 = g4[g2 * 4 + 2], gy2 = g4[g2 * 4 + 3];
                float l = fmaxf(x1, gx1), r = fminf(x2, gx2);
                float tp = fmaxf(y1, gy1), bo = fminf(y2, gy2);
                float v = 0.f;
                if (l < r && tp < bo) {
                    float inter = (r - l) * (bo - tp);
                    float ag = (gx2 - gx1) * (gy2 - gy1);
                    v = inter / (aa + ag - inter);
                }
                if (!inside) v = 0.f;
                if (v > best) { best = v; bg = g2; }
            }
            idxs = bg;
        }
        int a0 = at * 256;
        int a = a0 + t;
        float mx = 0.f;
        bool inside = false;
        if (a < ANCH) {
            float x1, y1, x2, y2;
            anchor_box(a, x1, y1, x2, y2);
            inside = (x1 >= 0.f) && (y1 >= 0.f) && (x2 < imv[1]) && (y2 < imv[0]);
            float aa = (x2 - x1) * (y2 - y1);
            for (int g2 = 0; g2 < NG; g2++) {
                float gx1 = g4[g2 * 4], gy1 = g4[g2 * 4 + 1], gx2 = g4[g2 * 4 + 2], gy2 = g4[g2 * 4 + 3];
                float l = fmaxf(x1, gx1), r = fminf(x2, gx2);
                float tp = fmaxf(y1, gy1), bo = fminf(y2, gy2);
                float v = 0.f;
                if (l < r && tp < bo) {
                    float inter = (r - l) * (bo - tp);
                    float ag = (gx2 - gx1) * (gy2 - gy1);
                    v = inter / (aa + ag - inter);
                }
                if (!inside) v = 0.f;
                buf[t * NG + g2] = v;
                mx = fmaxf(mx, v);
            }
        }
        __syncthreads();
        int rem = ANCH - a0;
        int cnt2 = (rem < 256 ? rem : 256) * NG;
        float* dst = iou_out + (b * ANCH + a0) * NG;
        for (int i = t; i < cnt2; i += 256) dst[i] = buf[i];
        if (a < ANCH) {
            float lv = (a == idxs) ? 1.f : 0.f;
            if (inside && mx > 0.7f) lv = 0.f;
            lab[b * ANCH + a] = lv;
        }
    }
}

// ---------- 3x3 conv as implicit GEMM, B-operand direct from global ----------
// BM=128 BN=64 BK=64 full-K. A staged via global_load_lds (XOR-swizzled LDS);
// B fragments loaded global->register ONE ITERATION AHEAD: the prefetch is
// issued before __syncthreads, so the barrier's vmcnt(0) drain covers it —
// no extra stall, and Bs LDS staging + its ds_reads disappear entirely.
__global__ __launch_bounds__(256) void k_conv(const u16* __restrict__ apad,
                                              const u16* __restrict__ wt,
                                              const float* __restrict__ b3,
                                              u16* __restrict__ act) {
    __shared__ __attribute__((aligned(16))) u16 As[128 * 64];   // 16 KB
    int L = blockIdx.x;
    int tid = threadIdx.x;

    int mb = (L & 7) + 8 * (L >> 6);
    int nb = (L >> 3) & 7;
    if (mb >= 116) return;
    int wave = tid >> 6, lane = tid & 63;
    int m0 = mb * 128;
    int n0 = nb * 64;
    int wr = wave >> 1, wn = wave & 1;
    int lm = lane & 15, lq = lane >> 4;
    int l7 = lm & 7;
    int lqo = lq * 8;

    f32x4 acc[4][2] = {};

    int rloc = tid >> 3;
    int cg = (tid & 7) ^ (rloc & 7);
    int aBase[4];
    for (int i = 0; i < 4; i++) {
        int m = m0 + i * 32 + rloc; if (m > MTOT - 1) m = MTOT - 1;
        int b = m / FHW; int hw = m - b * FHW;
        int h = hw / FW; int w = hw - h * FW;
        aBase[i] = ((b * HP + h) * WP + w) * 512 + cg * 8;
    }
    int bRow[2];
    for (int j = 0; j < 2; j++)
        bRow[j] = (n0 + wn * 32 + j * 16 + lm) * KTOT + lqo;

    u16* aL[4];
    for (int i = 0; i < 4; i++) aL[i] = &As[(i * 32 + wave * 8) * 64];

    // preload B for kk=0
    bf16x8 bNxt[2][2];
    #pragma unroll
    for (int ks = 0; ks < 2; ks++)
        #pragma unroll
        for (int j = 0; j < 2; j++)
            bNxt[ks][j] = *(const bf16x8*)&wt[bRow[j] + ks * 32];

    for (int kk = 0; kk < KTOT; kk += 64) {
        bf16x8 bCur[2][2];
        #pragma unroll
        for (int ks = 0; ks < 2; ks++)
            #pragma unroll
            for (int j = 0; j < 2; j++)
                bCur[ks][j] = bNxt[ks][j];

        int tap = kk >> 9;
        int ci0 = kk & 511;
        int dy = tap / 3, dx = tap - dy * 3;
        int aOfs = (dy * WP + dx) * 512 + ci0;
        gl2lds16(apad + aBase[0] + aOfs, aL[0]);
        gl2lds16(apad + aBase[1] + aOfs, aL[1]);
        gl2lds16(apad + aBase[2] + aOfs, aL[2]);
        gl2lds16(apad + aBase[3] + aOfs, aL[3]);

        int kn = kk + 64;
        if (kn < KTOT) {
            #pragma unroll
            for (int ks = 0; ks < 2; ks++)
                #pragma unroll
                for (int j = 0; j < 2; j++)
                    bNxt[ks][j] = *(const bf16x8*)&wt[bRow[j] + kn + ks * 32];
        }
        __syncthreads();   // drains A gl2lds AND the bNxt prefetch together

        bf16x8 a[2][4];
        #pragma unroll
        for (int ks = 0; ks < 2; ks++) {
            int slotb = ((ks * 4 + lq) ^ l7) * 8;
            #pragma unroll
            for (int i = 0; i < 4; i++)
                a[ks][i] = *(const bf16x8*)&As[(wr * 64 + i * 16 + lm) * 64 + slotb];
        }
        #pragma unroll
        for (int ks = 0; ks < 2; ks++)
            #pragma unroll
            for (int i = 0; i < 4; i++)
                #pragma unroll
                for (int j = 0; j < 2; j++)
                    acc[i][j] = __builtin_amdgcn_mfma_f32_16x16x32_bf16(a[ks][i], bCur[ks][j], acc[i][j], 0, 0, 0);
        __syncthreads();
    }

    // epilogue: bias + relu + bf16 act
    for (int j = 0; j < 2; j++) {
        int n = n0 + wn * 32 + j * 16 + lm;
        float bias = b3[n];
        for (int i = 0; i < 4; i++) {
            int mb2 = m0 + wr * 64 + i * 16 + lq * 4;
            for (int r = 0; r < 4; r++) {
                int m = mb2 + r;
                if (m < MTOT) {
                    float v = acc[i][j][r] + bias;
                    act[m * 512 + n] = f2bf(v > 0.f ? v : 0.f);
                }
            }
        }
    }
}

// ---------- fused 1x1 heads + softmax/bias + concat write ----------
// 463 blocks x 32 rows; wave pairs split K=512 into 256+256 (R4-proven).
__global__ __launch_bounds__(256) void k_post(const u16* __restrict__ act,
                                              const u16* __restrict__ whd,
                                              const float* __restrict__ bc,
                                              const float* __restrict__ bb,
                                              float* __restrict__ out) {
    __shared__ float Sl[4][16][68];
    int t = threadIdx.x;
    int wave = t >> 6, lane = t & 63, lm = lane & 15, lq = lane >> 4;
    int g = wave >> 1, kh = wave & 1;
    int m0 = blockIdx.x * 32;
    int mr = m0 + g * 16 + lm; if (mr > MTOT - 1) mr = MTOT - 1;
    const u16* arow = act + mr * 512;
    f32x4 acc[4] = {};
    #pragma unroll
    for (int s = 0; s < 8; s++) {
        int kk = kh * 256 + s * 32;
        bf16x8 a = *(const bf16x8*)&arow[kk + lq * 8];
        #pragma unroll
        for (int j = 0; j < 4; j++) {
            bf16x8 b = *(const bf16x8*)&whd[(j * 16 + lm) * 512 + kk + lq * 8];
            acc[j] = __builtin_amdgcn_mfma_f32_16x16x32_bf16(a, b, acc[j], 0, 0, 0);
        }
    }
    #pragma unroll
    for (int r = 0; r < 4; r++)
        #pragma unroll
        for (int j = 0; j < 4; j++)
            Sl[wave][lq * 4 + r][j * 16 + lm] = acc[j][r];
    __syncthreads();

    // epilogue: sum K-half partials + softmax/bias, coalesced write
    for (int i = t; i < 32 * 54; i += 256) {
        int row = i & 31, cc = i >> 5;
        int m = m0 + row;
        if (m >= MTOT) continue;
        int g2 = (row >> 4) * 2, rl = row & 15;
        float v;
        if (cc < 18) {
            int c0 = cc < 9 ? cc : cc - 9;
            float s0 = Sl[g2][rl][c0] + Sl[g2 + 1][rl][c0] + bc[c0];
            float s1 = Sl[g2][rl][c0 + 9] + Sl[g2 + 1][rl][c0 + 9] + bc[c0 + 9];
            float mx = fmaxf(s0, s1);
            float e0 = __expf(s0 - mx), e1 = __expf(s1 - mx);
            v = (cc < 9 ? e0 : e1) / (e0 + e1);
        } else {
            v = Sl[g2][rl][cc] + Sl[g2 + 1][rl][cc] + bb[cc - 18];
        }
        int b = m / FHW, hw = m - b * FHW;
        out[(b * 54 + cc) * FHW + hw] = v;
    }
}

extern "C" void kernel_launch(void* const* d_in, const int* in_sizes, int n_in,
                              void* d_out, int out_size, void* d_ws, size_t ws_size,
                              hipStream_t stream) {
    (void)in_sizes; (void)n_in; (void)out_size; (void)ws_size;
    const float* feats = (const float*)d_in[0];
    const float* w3    = (const float*)d_in[1];
    const float* b3    = (const float*)d_in[2];
    const float* wc    = (const float*)d_in[3];
    const float* bc    = (const float*)d_in[4];
    const float* wb    = (const float*)d_in[5];
    const float* bb    = (const float*)d_in[6];
    const float* gt    = (const float*)d_in[7];
    const float* im    = (const float*)d_in[8];
    float* out = (float*)d_out;
    char* ws = (char*)d_ws;

    // workspace layout (bytes)
    u16* apad = (u16*)(ws);                    // 8*39*52*512 bf16 = 16,613,376 B
    u16* wt   = (u16*)(ws + 16613376);         // 512*4608 bf16    =  4,718,592 B
    u16* whd  = (u16*)(ws + 21331968);         // 64*512 bf16      =     65,536 B
    u16* act  = (u16*)(ws + 21397504);         // 14800*512 bf16   = 15,155,200 B

    float* iou_out = out + 799200;
    float* lab     = out + 3463200;

    k_pre<<<dim3(PRE_TOT), dim3(256), 0, stream>>>(apad, w3, wt, wc, wb, whd, feats,
                                                   gt, im, iou_out, lab);
    k_conv<<<dim3(CONVB), dim3(256), 0, stream>>>(apad, wt, b3, act);
    k_post<<<dim3(463), dim3(256), 0, stream>>>(act, whd, bc, bb, out);
}

// Round 10
// 226.243 us; speedup vs baseline: 1.4482x; 1.4482x over previous
//
#include <hip/hip_runtime.h>

typedef unsigned short u16;
typedef unsigned int u32;
typedef float f32x4 __attribute__((ext_vector_type(4)));
typedef short bf16x8 __attribute__((ext_vector_type(8)));

#define NB 8
#define FH 37
#define FW 50
#define FHW 1850
#define MTOT 14800
#define CIN 512
#define KTOT 4608
#define HP 39
#define WP 52
#define ANCH 16650
#define NG 20

// k_pre block ranges
#define ZB 356            // pad-ring zero
#define WTB 512           // w3 repack (LDS transpose, 1 block per n)
#define WHB 128           // head-weight repack
#define TRB 3712          // NHWC transpose: 58 hw x 8 ctile x 8 img
#define PRE_TOT (ZB + WTB + WHB + TRB)

// k_conv block ranges
#define CONVB 960         // 116 mb x 8 nb (XCD swizzle; 32 dead blocks)
#define IOB 528           // 66 x 8 iou blocks ride along

// ---------- helpers ----------
__device__ __forceinline__ u16 f2bf(float f) {
    u32 u = __float_as_uint(f);
    u += 0x7fffu + ((u >> 16) & 1u);   // round-to-nearest-even
    return (u16)(u >> 16);
}

__device__ __forceinline__ void gl2lds16(const u16* g, u16* l) {
    __builtin_amdgcn_global_load_lds((const __attribute__((address_space(1))) void*)(g),
                                     (__attribute__((address_space(3))) void*)(l),
                                     16, 0, 0);
}

__device__ __forceinline__ void anchor_box(int a, float& x1, float& y1, float& x2, float& y2) {
    int x = a / 333;
    int rem = a - x * 333;
    int y = rem / 9;
    int r2 = rem - y * 9;
    int si = r2 / 3;
    int bi = r2 - si * 3;
    float s = (float)(8 << si);
    float fx = (float)x, fy = (float)y;
    float ax1, ay1, ax2, ay2;
    if (bi == 0)      { float h = s * 0.5f;  ax1 = fx - h; ay1 = fy - h; ax2 = fx + h; ay2 = fy + h; }
    else if (bi == 1) { float q = s * 0.25f; ax1 = fx - s; ay1 = fy - q; ax2 = fx + s; ay2 = fy + q; }
    else              { float q = s * 0.25f; ax1 = fx - q; ay1 = fy - s; ax2 = fx + q; ay2 = fy + s; }
    x1 = ax1 * 16.f; y1 = ay1 * 16.f; x2 = ax2 * 16.f; y2 = ay2 * 16.f;
}

// ---------- fused prep ----------
__global__ __launch_bounds__(256) void k_pre(u16* __restrict__ apad,
                                             const float* __restrict__ w3, u16* __restrict__ wt,
                                             const float* __restrict__ wc, const float* __restrict__ wb,
                                             u16* __restrict__ whd,
                                             const float* __restrict__ feats) {
    __shared__ __attribute__((aligned(16))) char smraw[18432];
    int blk = blockIdx.x;
    int t = threadIdx.x;

    if (blk < ZB) {
        // zero only the 1-px pad ring (interior overwritten by transpose)
        uint4* apad4 = (uint4*)apad;
        int i = blk * 256 + t;               // < 91136
        int img = i / 11392;
        int r = i - img * 11392;
        int u4;
        if (r < 3328) u4 = r;                                   // row 0
        else if (r < 6656) u4 = 126464 + (r - 3328);            // row 38
        else {
            int rp = r - 6656;
            int h = 1 + (rp >> 7);
            int c2 = rp & 127;
            int col = (c2 & 64) ? 51 : 0;
            u4 = (h * 52 + col) * 64 + (c2 & 63);
        }
        apad4[img * 129792 + u4] = make_uint4(0u, 0u, 0u, 0u);
    } else if (blk < ZB + WTB) {
        // w3[n] (512,3,3) -> wt[n][tap*512+ci], coalesced via LDS transpose
        float* lt = (float*)smraw;           // 4608 floats
        int n = blk - ZB;
        const float* src = w3 + n * KTOT;
        for (int i = t; i < KTOT; i += 256) lt[i] = src[i];
        __syncthreads();
        u16* dst = wt + n * KTOT;
        for (int o = t; o < KTOT; o += 256) {
            int tap = o >> 9, ci = o & 511;
            dst[o] = f2bf(lt[ci * 9 + tap]);
        }
    } else if (blk < ZB + WTB + WHB) {
        int i = (blk - ZB - WTB) * 256 + t;
        int n = i >> 9;
        int ci = i & 511;
        float v = 0.f;
        if (n < 18) v = wc[n * 512 + ci];
        else if (n < 54) v = wb[(n - 18) * 512 + ci];
        whd[i] = f2bf(v);
    } else {
        // feats (B,512,37,50) f32 -> apad (B,39,52,512) bf16 interior.
        // Tile: 32 hw x 64 c; stores pack 2 channels/lane (u32, 128-B segments).
        float* tile = (float*)smraw;         // 64 x 33 floats
        int q = blk - ZB - WTB - WHB;
        int xt = q % 58;
        int r2 = q / 58;
        int ct = r2 & 7;                     // 8 c-tiles of 64
        int img = r2 >> 3;
        int hw0 = xt * 32, c0 = ct * 64;
        int lx = t & 31, ly = t >> 5;        // ly 0..7
        #pragma unroll
        for (int rr = 0; rr < 8; rr++) {
            int cl = ly + rr * 8;            // 0..63
            int hw = hw0 + lx;
            if (hw < FHW) tile[cl * 33 + lx] = feats[(img * 512 + c0 + cl) * FHW + hw];
        }
        __syncthreads();
        #pragma unroll
        for (int rr = 0; rr < 4; rr++) {
            int hwl = ly + rr * 8;           // 0..31
            int hw2 = hw0 + hwl;
            if (hw2 < FHW) {
                int h = hw2 / FW, w = hw2 - h * FW;
                float v0 = tile[(2 * lx) * 33 + hwl];
                float v1 = tile[(2 * lx + 1) * 33 + hwl];
                u32 pk = (u32)f2bf(v0) | ((u32)f2bf(v1) << 16);
                u32* dst = (u32*)&apad[(((img * HP) + h + 1) * WP + (w + 1)) * 512 + c0];
                dst[lx] = pk;
            }
        }
    }
}

// ---------- 3x3 conv as implicit GEMM (double-buffered LDS) + IoU tail ----------
// BM=128 BN=64 BK=64 full-K. One barrier per K-iter: prefetch for iter k+1 is
// issued BEFORE iter k's MFMA phase, so the end-of-iter vmcnt drain overlaps
// the MFMA work instead of stalling on just-issued loads (R9 lesson: fragments
// must come from LDS — only wave-contiguous staging goes direct to global).
__global__ __launch_bounds__(256) void k_conv(const u16* __restrict__ apad,
                                              const u16* __restrict__ wt,
                                              const float* __restrict__ b3,
                                              u16* __restrict__ act,
                                              const float* __restrict__ gt,
                                              const float* __restrict__ im,
                                              float* __restrict__ iou_out,
                                              float* __restrict__ lab) {
    __shared__ __attribute__((aligned(16))) char sm[49152];
    __shared__ int idxs;
    int L = blockIdx.x;
    int tid = threadIdx.x;

    if (L < CONVB) {
        u16* As0 = (u16*)sm;                // 16 KB
        u16* As1 = (u16*)(sm + 16384);      // 16 KB
        u16* Bs0 = (u16*)(sm + 32768);      //  8 KB
        u16* Bs1 = (u16*)(sm + 40960);      //  8 KB
        int mb = (L & 7) + 8 * (L >> 6);
        int nb = (L >> 3) & 7;
        if (mb >= 116) return;
        int wave = tid >> 6, lane = tid & 63;
        int m0 = mb * 128;
        int n0 = nb * 64;
        int wr = wave >> 1, wn = wave & 1;
        int lm = lane & 15, lq = lane >> 4;
        int l7 = lm & 7;

        f32x4 acc[4][2] = {};

        int rloc = tid >> 3;
        int cg = (tid & 7) ^ (rloc & 7);
        int aBase[4], bBase[2];
        for (int i = 0; i < 4; i++) {
            int m = m0 + i * 32 + rloc; if (m > MTOT - 1) m = MTOT - 1;
            int b = m / FHW; int hw = m - b * FHW;
            int h = hw / FW; int w = hw - h * FW;
            aBase[i] = ((b * HP + h) * WP + w) * 512 + cg * 8;
        }
        for (int j = 0; j < 2; j++)
            bBase[j] = (n0 + j * 32 + rloc) * KTOT + cg * 8;

        int wo = wave * 8 * 64;              // wave's staging offset within a buffer

        auto issue = [&](int kkn, u16* WA, u16* WB) {
            int tap = kkn >> 9;
            int ci0 = kkn & 511;
            int dy = tap / 3, dx = tap - dy * 3;
            int aOfs = (dy * WP + dx) * 512 + ci0;
            gl2lds16(apad + aBase[0] + aOfs, &WA[wo]);
            gl2lds16(apad + aBase[1] + aOfs, &WA[wo + 2048]);
            gl2lds16(apad + aBase[2] + aOfs, &WA[wo + 4096]);
            gl2lds16(apad + aBase[3] + aOfs, &WA[wo + 6144]);
            gl2lds16(wt + bBase[0] + kkn, &WB[wo]);
            gl2lds16(wt + bBase[1] + kkn, &WB[wo + 2048]);
        };
        auto step = [&](int kk, const u16* RA, const u16* RB, u16* WA, u16* WB) {
            int kn = kk + 64;
            if (kn < KTOT) issue(kn, WA, WB);
            bf16x8 a[2][4], b[2][2];
            #pragma unroll
            for (int ks = 0; ks < 2; ks++) {
                int slotb = ((ks * 4 + lq) ^ l7) * 8;
                #pragma unroll
                for (int i = 0; i < 4; i++)
                    a[ks][i] = *(const bf16x8*)&RA[(wr * 64 + i * 16 + lm) * 64 + slotb];
                #pragma unroll
                for (int j = 0; j < 2; j++)
                    b[ks][j] = *(const bf16x8*)&RB[(wn * 32 + j * 16 + lm) * 64 + slotb];
            }
            #pragma unroll
            for (int ks = 0; ks < 2; ks++)
                #pragma unroll
                for (int i = 0; i < 4; i++)
                    #pragma unroll
                    for (int j = 0; j < 2; j++)
                        acc[i][j] = __builtin_amdgcn_mfma_f32_16x16x32_bf16(a[ks][i], b[ks][j], acc[i][j], 0, 0, 0);
            __syncthreads();
        };

        issue(0, As0, Bs0);
        __syncthreads();
        for (int kk = 0; kk < KTOT; kk += 128) {
            step(kk,      As0, Bs0, As1, Bs1);
            step(kk + 64, As1, Bs1, As0, Bs0);
        }

        // epilogue: bias + relu + bf16 act
        for (int j = 0; j < 2; j++) {
            int n = n0 + wn * 32 + j * 16 + lm;
            float bias = b3[n];
            for (int i = 0; i < 4; i++) {
                int mb2 = m0 + wr * 64 + i * 16 + lq * 4;
                for (int r = 0; r < 4; r++) {
                    int m = mb2 + r;
                    if (m < MTOT) {
                        float v = acc[i][j][r] + bias;
                        act[m * 512 + n] = f2bf(v > 0.f ? v : 0.f);
                    }
                }
            }
        }
    } else {
        // IoU matrix + labels (idx fused)
        float* g4 = (float*)sm;              // 80 floats
        float* imv = g4 + 80;                // 2
        float* buf = g4 + 84;                // 256*20
        int q = L - CONVB;
        int at = q % 66;
        int b = q / 66;
        int t = tid;
        if (t < NG * 4) g4[t] = gt[b * NG * 4 + t];
        if (t < 2) imv[t] = im[t];
        __syncthreads();
        if (t == 0) {
            float x1, y1, x2, y2;
            anchor_box(19, x1, y1, x2, y2);
            bool inside = (x1 >= 0.f) && (y1 >= 0.f) && (x2 < imv[1]) && (y2 < imv[0]);
            float aa = (x2 - x1) * (y2 - y1);
            float best = -1.f; int bg = 0;
            for (int g2 = 0; g2 < NG; g2++) {
                float gx1 = g4[g2 * 4], gy1 = g4[g2 * 4 + 1], gx2 = g4[g2 * 4 + 2], gy2 = g4[g2 * 4 + 3];
                float l = fmaxf(x1, gx1), r = fminf(x2, gx2);
                float tp = fmaxf(y1, gy1), bo = fminf(y2, gy2);
                float v = 0.f;
                if (l < r && tp < bo) {
                    float inter = (r - l) * (bo - tp);
                    float ag = (gx2 - gx1) * (gy2 - gy1);
                    v = inter / (aa + ag - inter);
                }
                if (!inside) v = 0.f;
                if (v > best) { best = v; bg = g2; }
            }
            idxs = bg;
        }
        int a0 = at * 256;
        int a = a0 + t;
        float mx = 0.f;
        bool inside = false;
        if (a < ANCH) {
            float x1, y1, x2, y2;
            anchor_box(a, x1, y1, x2, y2);
            inside = (x1 >= 0.f) && (y1 >= 0.f) && (x2 < imv[1]) && (y2 < imv[0]);
            float aa = (x2 - x1) * (y2 - y1);
            for (int g2 = 0; g2 < NG; g2++) {
                float gx1 = g4[g2 * 4], gy1 = g4[g2 * 4 + 1], gx2 = g4[g2 * 4 + 2], gy2 = g4[g2 * 4 + 3];
                float l = fmaxf(x1, gx1), r = fminf(x2, gx2);
                float tp = fmaxf(y1, gy1), bo = fminf(y2, gy2);
                float v = 0.f;
                if (l < r && tp < bo) {
                    float inter = (r - l) * (bo - tp);
                    float ag = (gx2 - gx1) * (gy2 - gy1);
                    v = inter / (aa + ag - inter);
                }
                if (!inside) v = 0.f;
                buf[t * NG + g2] = v;
                mx = fmaxf(mx, v);
            }
        }
        __syncthreads();
        int rem = ANCH - a0;
        int cnt2 = (rem < 256 ? rem : 256) * NG;
        float* dst = iou_out + (b * ANCH + a0) * NG;
        for (int i = t; i < cnt2; i += 256) dst[i] = buf[i];
        if (a < ANCH) {
            float lv = (a == idxs) ? 1.f : 0.f;
            if (inside && mx > 0.7f) lv = 0.f;
            lab[b * ANCH + a] = lv;
        }
    }
}

// ---------- fused 1x1 heads + softmax/bias + concat write ----------
// 232 blocks x 4 waves; each wave: 16 rows x 64 cols GEMM -> LDS -> epilogue.
__global__ __launch_bounds__(256) void k_post(const u16* __restrict__ act,
                                              const u16* __restrict__ whd,
                                              const float* __restrict__ bc,
                                              const float* __restrict__ bb,
                                              float* __restrict__ out) {
    __shared__ float Sl[4 * 16 * 65];
    int tid = threadIdx.x;
    int wave = tid >> 6, lane = tid & 63;
    int lm = lane & 15, lq = lane >> 4;
    int m0 = blockIdx.x * 64 + wave * 16;
    int mr = m0 + lm; if (mr > MTOT - 1) mr = MTOT - 1;
    const u16* arow = act + mr * 512;
    f32x4 acc[4] = {};
    for (int kk = 0; kk < 512; kk += 32) {
        bf16x8 a = *(const bf16x8*)&arow[kk + lq * 8];
        #pragma unroll
        for (int j = 0; j < 4; j++) {
            bf16x8 b = *(const bf16x8*)&whd[(j * 16 + lm) * 512 + kk + lq * 8];
            acc[j] = __builtin_amdgcn_mfma_f32_16x16x32_bf16(a, b, acc[j], 0, 0, 0);
        }
    }
    float* S = &Sl[wave * 1040];
    #pragma unroll
    for (int r = 0; r < 4; r++)
        #pragma unroll
        for (int j = 0; j < 4; j++)
            S[(lq * 4 + r) * 65 + j * 16 + lm] = acc[j][r];
    __syncthreads();
    int r16 = lane & 15, cg = lane >> 4;
    int m = m0 + r16;
    if (m < MTOT) {
        int b = m / FHW, hw = m - b * FHW;
        const float* Sr = &S[r16 * 65];
        #pragma unroll
        for (int k = 0; k < 14; k++) {
            int c = cg + 4 * k;
            if (c >= 54) break;
            float v;
            if (c < 18) {
                int c0 = c < 9 ? c : c - 9;
                float s0 = Sr[c0] + bc[c0];
                float s1 = Sr[c0 + 9] + bc[c0 + 9];
                float mx = fmaxf(s0, s1);
                float e0 = __expf(s0 - mx), e1 = __expf(s1 - mx);
                v = (c < 9 ? e0 : e1) / (e0 + e1);
            } else {
                v = Sr[c] + bb[c - 18];
            }
            out[(b * 54 + c) * FHW + hw] = v;
        }
    }
}

extern "C" void kernel_launch(void* const* d_in, const int* in_sizes, int n_in,
                              void* d_out, int out_size, void* d_ws, size_t ws_size,
                              hipStream_t stream) {
    (void)in_sizes; (void)n_in; (void)out_size; (void)ws_size;
    const float* feats = (const float*)d_in[0];
    const float* w3    = (const float*)d_in[1];
    const float* b3    = (const float*)d_in[2];
    const float* wc    = (const float*)d_in[3];
    const float* bc    = (const float*)d_in[4];
    const float* wb    = (const float*)d_in[5];
    const float* bb    = (const float*)d_in[6];
    const float* gt    = (const float*)d_in[7];
    const float* im    = (const float*)d_in[8];
    float* out = (float*)d_out;
    char* ws = (char*)d_ws;

    // workspace layout (bytes)
    u16* apad = (u16*)(ws);                    // 8*39*52*512 bf16 = 16,613,376 B
    u16* wt   = (u16*)(ws + 16613376);         // 512*4608 bf16    =  4,718,592 B
    u16* whd  = (u16*)(ws + 21331968);         // 64*512 bf16      =     65,536 B
    u16* act  = (u16*)(ws + 21397504);         // 14800*512 bf16   = 15,155,200 B

    float* iou_out = out + 799200;
    float* lab     = out + 3463200;

    k_pre<<<dim3(PRE_TOT), dim3(256), 0, stream>>>(apad, w3, wt, wc, wb, whd, feats);
    k_conv<<<dim3(CONVB + IOB), dim3(256), 0, stream>>>(apad, wt, b3, act, gt, im, iou_out, lab);
    k_post<<<dim3(232), dim3(256), 0, stream>>>(act, whd, bc, bb, out);
}

// Round 11
// 201.880 us; speedup vs baseline: 1.6229x; 1.1207x over previous
//
#include <hip/hip_runtime.h>

typedef unsigned short u16;
typedef unsigned int u32;
typedef float f32x4 __attribute__((ext_vector_type(4)));
typedef short bf16x8 __attribute__((ext_vector_type(8)));

#define NB 8
#define FH 37
#define FW 50
#define FHW 1850
#define MTOT 14800
#define CIN 512
#define KTOT 4608
#define HP 39
#define WP 52
#define ANCH 16650
#define NG 20

// k_pre block ranges
#define ZB 356            // pad-ring zero
#define WTB 512           // w3 repack (LDS transpose, 1 block per n)
#define WHB 128           // head-weight repack
#define TRB 3712          // NHWC transpose: 58 hw x 8 ctile x 8 img
#define PRE_TOT (ZB + WTB + WHB + TRB)

// k_conv block ranges
#define CONVB 960         // 116 mb x 8 nb (XCD swizzle; 32 dead blocks)
#define IOB 528           // 66 x 8 iou blocks ride along

// ---------- helpers ----------
__device__ __forceinline__ u16 f2bf(float f) {
    u32 u = __float_as_uint(f);
    u += 0x7fffu + ((u >> 16) & 1u);   // round-to-nearest-even
    return (u16)(u >> 16);
}

__device__ __forceinline__ void gl2lds16(const u16* g, u16* l) {
    __builtin_amdgcn_global_load_lds((const __attribute__((address_space(1))) void*)(g),
                                     (__attribute__((address_space(3))) void*)(l),
                                     16, 0, 0);
}

__device__ __forceinline__ void anchor_box(int a, float& x1, float& y1, float& x2, float& y2) {
    int x = a / 333;
    int rem = a - x * 333;
    int y = rem / 9;
    int r2 = rem - y * 9;
    int si = r2 / 3;
    int bi = r2 - si * 3;
    float s = (float)(8 << si);
    float fx = (float)x, fy = (float)y;
    float ax1, ay1, ax2, ay2;
    if (bi == 0)      { float h = s * 0.5f;  ax1 = fx - h; ay1 = fy - h; ax2 = fx + h; ay2 = fy + h; }
    else if (bi == 1) { float q = s * 0.25f; ax1 = fx - s; ay1 = fy - q; ax2 = fx + s; ay2 = fy + q; }
    else              { float q = s * 0.25f; ax1 = fx - q; ay1 = fy - s; ax2 = fx + q; ay2 = fy + s; }
    x1 = ax1 * 16.f; y1 = ay1 * 16.f; x2 = ax2 * 16.f; y2 = ay2 * 16.f;
}

// ---------- fused prep ----------
__global__ __launch_bounds__(256) void k_pre(u16* __restrict__ apad,
                                             const float* __restrict__ w3, u16* __restrict__ wt,
                                             const float* __restrict__ wc, const float* __restrict__ wb,
                                             u16* __restrict__ whd,
                                             const float* __restrict__ feats) {
    __shared__ __attribute__((aligned(16))) char smraw[18432];
    int blk = blockIdx.x;
    int t = threadIdx.x;

    if (blk < ZB) {
        // zero only the 1-px pad ring (interior overwritten by transpose)
        uint4* apad4 = (uint4*)apad;
        int i = blk * 256 + t;               // < 91136
        int img = i / 11392;
        int r = i - img * 11392;
        int u4;
        if (r < 3328) u4 = r;                                   // row 0
        else if (r < 6656) u4 = 126464 + (r - 3328);            // row 38
        else {
            int rp = r - 6656;
            int h = 1 + (rp >> 7);
            int c2 = rp & 127;
            int col = (c2 & 64) ? 51 : 0;
            u4 = (h * 52 + col) * 64 + (c2 & 63);
        }
        apad4[img * 129792 + u4] = make_uint4(0u, 0u, 0u, 0u);
    } else if (blk < ZB + WTB) {
        // w3[n] (512,3,3) -> wt[n][tap*512+ci], coalesced via LDS transpose
        float* lt = (float*)smraw;           // 4608 floats
        int n = blk - ZB;
        const float* src = w3 + n * KTOT;
        for (int i = t; i < KTOT; i += 256) lt[i] = src[i];
        __syncthreads();
        u16* dst = wt + n * KTOT;
        for (int o = t; o < KTOT; o += 256) {
            int tap = o >> 9, ci = o & 511;
            dst[o] = f2bf(lt[ci * 9 + tap]);
        }
    } else if (blk < ZB + WTB + WHB) {
        int i = (blk - ZB - WTB) * 256 + t;
        int n = i >> 9;
        int ci = i & 511;
        float v = 0.f;
        if (n < 18) v = wc[n * 512 + ci];
        else if (n < 54) v = wb[(n - 18) * 512 + ci];
        whd[i] = f2bf(v);
    } else {
        // feats (B,512,37,50) f32 -> apad (B,39,52,512) bf16 interior.
        // Tile: 32 hw x 64 c; stores pack 2 channels/lane (u32, 128-B segments).
        float* tile = (float*)smraw;         // 64 x 33 floats
        int q = blk - ZB - WTB - WHB;
        int xt = q % 58;
        int r2 = q / 58;
        int ct = r2 & 7;                     // 8 c-tiles of 64
        int img = r2 >> 3;
        int hw0 = xt * 32, c0 = ct * 64;
        int lx = t & 31, ly = t >> 5;        // ly 0..7
        #pragma unroll
        for (int rr = 0; rr < 8; rr++) {
            int cl = ly + rr * 8;            // 0..63
            int hw = hw0 + lx;
            if (hw < FHW) tile[cl * 33 + lx] = feats[(img * 512 + c0 + cl) * FHW + hw];
        }
        __syncthreads();
        #pragma unroll
        for (int rr = 0; rr < 4; rr++) {
            int hwl = ly + rr * 8;           // 0..31
            int hw2 = hw0 + hwl;
            if (hw2 < FHW) {
                int h = hw2 / FW, w = hw2 - h * FW;
                float v0 = tile[(2 * lx) * 33 + hwl];
                float v1 = tile[(2 * lx + 1) * 33 + hwl];
                u32 pk = (u32)f2bf(v0) | ((u32)f2bf(v1) << 16);
                u32* dst = (u32*)&apad[(((img * HP) + h + 1) * WP + (w + 1)) * 512 + c0];
                dst[lx] = pk;
            }
        }
    }
}

// ---------- 3x3 conv as implicit GEMM + IoU tail ----------
// BM=128 BN=64 BK=64 full-K, bf16 act epilogue. XCD decode: all 8 nb of one
// mb share L%8 (one XCD) for A-tile L2 reuse. 2-barrier K-loop (the proven
// plateau structure: split-K/dbuf/B-direct/atomics all measured worse).
__global__ __launch_bounds__(256) void k_conv(const u16* __restrict__ apad,
                                              const u16* __restrict__ wt,
                                              const float* __restrict__ b3,
                                              u16* __restrict__ act,
                                              const float* __restrict__ gt,
                                              const float* __restrict__ im,
                                              float* __restrict__ iou_out,
                                              float* __restrict__ lab) {
    __shared__ __attribute__((aligned(16))) char sm[24576];
    __shared__ int idxs;
    int L = blockIdx.x;
    int tid = threadIdx.x;

    if (L < CONVB) {
        u16* As = (u16*)sm;                 // 128x64 bf16, 16 KB
        u16* Bs = (u16*)(sm + 16384);       // 64x64 bf16, 8 KB
        int mb = (L & 7) + 8 * (L >> 6);
        int nb = (L >> 3) & 7;
        if (mb >= 116) return;
        int wave = tid >> 6, lane = tid & 63;
        int m0 = mb * 128;
        int n0 = nb * 64;
        int wr = wave >> 1, wn = wave & 1;
        int lm = lane & 15, lq = lane >> 4;
        int l7 = lm & 7;

        f32x4 acc[4][2] = {};

        int rloc = tid >> 3;
        int cg = (tid & 7) ^ (rloc & 7);
        int aBase[4], bBase[2];
        for (int i = 0; i < 4; i++) {
            int m = m0 + i * 32 + rloc; if (m > MTOT - 1) m = MTOT - 1;
            int b = m / FHW; int hw = m - b * FHW;
            int h = hw / FW; int w = hw - h * FW;
            aBase[i] = ((b * HP + h) * WP + w) * 512 + cg * 8;
        }
        for (int j = 0; j < 2; j++)
            bBase[j] = (n0 + j * 32 + rloc) * KTOT + cg * 8;

        u16* aL[4]; u16* bL[2];
        for (int i = 0; i < 4; i++) aL[i] = &As[(i * 32 + wave * 8) * 64];
        for (int j = 0; j < 2; j++) bL[j] = &Bs[(j * 32 + wave * 8) * 64];

        for (int kk = 0; kk < KTOT; kk += 64) {
            int tap = kk >> 9;
            int ci0 = kk & 511;
            int dy = tap / 3, dx = tap - dy * 3;
            int aOfs = (dy * WP + dx) * 512 + ci0;
            gl2lds16(apad + aBase[0] + aOfs, aL[0]);
            gl2lds16(apad + aBase[1] + aOfs, aL[1]);
            gl2lds16(apad + aBase[2] + aOfs, aL[2]);
            gl2lds16(apad + aBase[3] + aOfs, aL[3]);
            gl2lds16(wt + bBase[0] + kk, bL[0]);
            gl2lds16(wt + bBase[1] + kk, bL[1]);
            __syncthreads();
            bf16x8 a[2][4], b[2][2];
            #pragma unroll
            for (int ks = 0; ks < 2; ks++) {
                int slotb = ((ks * 4 + lq) ^ l7) * 8;
                #pragma unroll
                for (int i = 0; i < 4; i++)
                    a[ks][i] = *(const bf16x8*)&As[(wr * 64 + i * 16 + lm) * 64 + slotb];
                #pragma unroll
                for (int j = 0; j < 2; j++)
                    b[ks][j] = *(const bf16x8*)&Bs[(wn * 32 + j * 16 + lm) * 64 + slotb];
            }
            #pragma unroll
            for (int ks = 0; ks < 2; ks++)
                #pragma unroll
                for (int i = 0; i < 4; i++)
                    #pragma unroll
                    for (int j = 0; j < 2; j++)
                        acc[i][j] = __builtin_amdgcn_mfma_f32_16x16x32_bf16(a[ks][i], b[ks][j], acc[i][j], 0, 0, 0);
            __syncthreads();
        }

        // epilogue: bias + relu + bf16 act
        for (int j = 0; j < 2; j++) {
            int n = n0 + wn * 32 + j * 16 + lm;
            float bias = b3[n];
            for (int i = 0; i < 4; i++) {
                int mb2 = m0 + wr * 64 + i * 16 + lq * 4;
                for (int r = 0; r < 4; r++) {
                    int m = mb2 + r;
                    if (m < MTOT) {
                        float v = acc[i][j][r] + bias;
                        act[m * 512 + n] = f2bf(v > 0.f ? v : 0.f);
                    }
                }
            }
        }
    } else {
        // IoU matrix + labels (idx fused)
        float* g4 = (float*)sm;              // 80 floats
        float* imv = g4 + 80;                // 2
        float* buf = g4 + 84;                // 256*20
        int q = L - CONVB;
        int at = q % 66;
        int b = q / 66;
        int t = tid;
        if (t < NG * 4) g4[t] = gt[b * NG * 4 + t];
        if (t < 2) imv[t] = im[t];
        __syncthreads();
        if (t == 0) {
            float x1, y1, x2, y2;
            anchor_box(19, x1, y1, x2, y2);
            bool inside = (x1 >= 0.f) && (y1 >= 0.f) && (x2 < imv[1]) && (y2 < imv[0]);
            float aa = (x2 - x1) * (y2 - y1);
            float best = -1.f; int bg = 0;
            for (int g2 = 0; g2 < NG; g2++) {
                float gx1 = g4[g2 * 4], gy1 = g4[g2 * 4 + 1], gx2 = g4[g2 * 4 + 2], gy2 = g4[g2 * 4 + 3];
                float l = fmaxf(x1, gx1), r = fminf(x2, gx2);
                float tp = fmaxf(y1, gy1), bo = fminf(y2, gy2);
                float v = 0.f;
                if (l < r && tp < bo) {
                    float inter = (r - l) * (bo - tp);
                    float ag = (gx2 - gx1) * (gy2 - gy1);
                    v = inter / (aa + ag - inter);
                }
                if (!inside) v = 0.f;
                if (v > best) { best = v; bg = g2; }
            }
            idxs = bg;
        }
        int a0 = at * 256;
        int a = a0 + t;
        float mx = 0.f;
        bool inside = false;
        if (a < ANCH) {
            float x1, y1, x2, y2;
            anchor_box(a, x1, y1, x2, y2);
            inside = (x1 >= 0.f) && (y1 >= 0.f) && (x2 < imv[1]) && (y2 < imv[0]);
            float aa = (x2 - x1) * (y2 - y1);
            for (int g2 = 0; g2 < NG; g2++) {
                float gx1 = g4[g2 * 4], gy1 = g4[g2 * 4 + 1], gx2 = g4[g2 * 4 + 2], gy2 = g4[g2 * 4 + 3];
                float l = fmaxf(x1, gx1), r = fminf(x2, gx2);
                float tp = fmaxf(y1, gy1), bo = fminf(y2, gy2);
                float v = 0.f;
                if (l < r && tp < bo) {
                    float inter = (r - l) * (bo - tp);
                    float ag = (gx2 - gx1) * (gy2 - gy1);
                    v = inter / (aa + ag - inter);
                }
                if (!inside) v = 0.f;
                buf[t * NG + g2] = v;
                mx = fmaxf(mx, v);
            }
        }
        __syncthreads();
        int rem = ANCH - a0;
        int cnt2 = (rem < 256 ? rem : 256) * NG;
        float* dst = iou_out + (b * ANCH + a0) * NG;
        for (int i = t; i < cnt2; i += 256) dst[i] = buf[i];
        if (a < ANCH) {
            float lv = (a == idxs) ? 1.f : 0.f;
            if (inside && mx > 0.7f) lv = 0.f;
            lab[b * ANCH + a] = lv;
        }
    }
}

// ---------- fused 1x1 heads + softmax/bias + concat write ----------
// 232 blocks x 4 waves; each wave: 16 rows x 64 cols GEMM -> LDS -> epilogue.
__global__ __launch_bounds__(256) void k_post(const u16* __restrict__ act,
                                              const u16* __restrict__ whd,
                                              const float* __restrict__ bc,
                                              const float* __restrict__ bb,
                                              float* __restrict__ out) {
    __shared__ float Sl[4 * 16 * 65];
    int tid = threadIdx.x;
    int wave = tid >> 6, lane = tid & 63;
    int lm = lane & 15, lq = lane >> 4;
    int m0 = blockIdx.x * 64 + wave * 16;
    int mr = m0 + lm; if (mr > MTOT - 1) mr = MTOT - 1;
    const u16* arow = act + mr * 512;
    f32x4 acc[4] = {};
    for (int kk = 0; kk < 512; kk += 32) {
        bf16x8 a = *(const bf16x8*)&arow[kk + lq * 8];
        #pragma unroll
        for (int j = 0; j < 4; j++) {
            bf16x8 b = *(const bf16x8*)&whd[(j * 16 + lm) * 512 + kk + lq * 8];
            acc[j] = __builtin_amdgcn_mfma_f32_16x16x32_bf16(a, b, acc[j], 0, 0, 0);
        }
    }
    float* S = &Sl[wave * 1040];
    #pragma unroll
    for (int r = 0; r < 4; r++)
        #pragma unroll
        for (int j = 0; j < 4; j++)
            S[(lq * 4 + r) * 65 + j * 16 + lm] = acc[j][r];
    __syncthreads();
    int r16 = lane & 15, cg = lane >> 4;
    int m = m0 + r16;
    if (m < MTOT) {
        int b = m / FHW, hw = m - b * FHW;
        const float* Sr = &S[r16 * 65];
        #pragma unroll
        for (int k = 0; k < 14; k++) {
            int c = cg + 4 * k;
            if (c >= 54) break;
            float v;
            if (c < 18) {
                int c0 = c < 9 ? c : c - 9;
                float s0 = Sr[c0] + bc[c0];
                float s1 = Sr[c0 + 9] + bc[c0 + 9];
                float mx = fmaxf(s0, s1);
                float e0 = __expf(s0 - mx), e1 = __expf(s1 - mx);
                v = (c < 9 ? e0 : e1) / (e0 + e1);
            } else {
                v = Sr[c] + bb[c - 18];
            }
            out[(b * 54 + c) * FHW + hw] = v;
        }
    }
}

extern "C" void kernel_launch(void* const* d_in, const int* in_sizes, int n_in,
                              void* d_out, int out_size, void* d_ws, size_t ws_size,
                              hipStream_t stream) {
    (void)in_sizes; (void)n_in; (void)out_size; (void)ws_size;
    const float* feats = (const float*)d_in[0];
    const float* w3    = (const float*)d_in[1];
    const float* b3    = (const float*)d_in[2];
    const float* wc    = (const float*)d_in[3];
    const float* bc    = (const float*)d_in[4];
    const float* wb    = (const float*)d_in[5];
    const float* bb    = (const float*)d_in[6];
    const float* gt    = (const float*)d_in[7];
    const float* im    = (const float*)d_in[8];
    float* out = (float*)d_out;
    char* ws = (char*)d_ws;

    // workspace layout (bytes)
    u16* apad = (u16*)(ws);                    // 8*39*52*512 bf16 = 16,613,376 B
    u16* wt   = (u16*)(ws + 16613376);         // 512*4608 bf16    =  4,718,592 B
    u16* whd  = (u16*)(ws + 21331968);         // 64*512 bf16      =     65,536 B
    u16* act  = (u16*)(ws + 21397504);         // 14800*512 bf16   = 15,155,200 B

    float* iou_out = out + 799200;
    float* lab     = out + 3463200;

    k_pre<<<dim3(PRE_TOT), dim3(256), 0, stream>>>(apad, w3, wt, wc, wb, whd, feats);
    k_conv<<<dim3(CONVB + IOB), dim3(256), 0, stream>>>(apad, wt, b3, act, gt, im, iou_out, lab);
    k_post<<<dim3(232), dim3(256), 0, stream>>>(act, whd, bc, bb, out);
}